// Round 1
// baseline (95.026 us; speedup 1.0000x reference)
//
#include <hip/hip_runtime.h>
#include <math.h>

// PlaceCellNetwork: C=4 one-layer dictionaries, B=2048 inputs.
//   Wx[c,b,o] = sum_i X[b,i] * W[c,o,i]
//   100 iterations of y <- max((y + dt*(-y + Wx - b - Y@M_off^T) - l1)/(l2+diag), 0)
// Convergence predicate provably never fires in 100 iters (contraction factor
// ~0.985/iter, err stays ~0.2 >> 1e-4) -> run exactly MAXITER iterations, no
// global sync, errTrack unused. Rows (c,b) are independent -> fully parallel.
// Real input has M == I exactly -> M_off == 0: per-block exact-zero check
// selects a register-only elementwise fast path; general path kept correct.

#define C_ 4
#define IN_ 64
#define OUT_ 128
#define B_ 2048
#define MAXITER_ 100
#define LBD1_ 0.005f
#define LBD2_ 0.005f

#define THREADS_ 256
#define ROWS_PER_BLOCK_ 16   // 2 rows/thread, 32 col-threads (4 cols each)
#define WT_PITCH_ 132        // 132 % 32 == 4 -> conflict-free transpose writes; 132*4 % 16 == 0 -> aligned float4 rows

__global__ __launch_bounds__(THREADS_)
void pcn_kernel(const float* __restrict__ X,
                const float* __restrict__ W,
                const float* __restrict__ M,
                const float* __restrict__ bvec,
                float* __restrict__ out)
{
    // smem: W^T (64 x 132 floats) during the Wx GEMM; re-used as Y_lds (16x128)
    // in the (never-taken-in-practice) general path.
    __shared__ __align__(16) float smem[IN_ * WT_PITCH_];
    __shared__ __align__(16) float xs[ROWS_PER_BLOCK_ * IN_];
    __shared__ float red[4];

    const int tid   = threadIdx.x;
    const int bx    = blockIdx.x;
    const int c     = bx >> 7;        // 128 chunks per c
    const int chunk = bx & 127;
    const int k     = tid & 31;       // column group: cols 4k..4k+3
    const int rg    = tid >> 5;       // 0..7 row groups
    const int r0    = 2 * rg;         // local rows r0, r0+1
    const int rowg0 = chunk * ROWS_PER_BLOCK_ + r0;

    const float* Wc = W + c * (OUT_ * IN_);
    const float* Mc = M + c * (OUT_ * OUT_);

    // ---- stage W^T into LDS: WT[i][o] = W[o][i] ------------------------
    {
        const int o    = tid >> 1;
        const int half = tid & 1;
        const float4* wrow = (const float4*)(Wc + o * IN_ + half * 32);
        #pragma unroll
        for (int j4 = 0; j4 < 8; ++j4) {
            float4 v = wrow[j4];
            int i0 = half * 32 + j4 * 4;
            smem[(i0 + 0) * WT_PITCH_ + o] = v.x;
            smem[(i0 + 1) * WT_PITCH_ + o] = v.y;
            smem[(i0 + 2) * WT_PITCH_ + o] = v.z;
            smem[(i0 + 3) * WT_PITCH_ + o] = v.w;
        }
    }
    // ---- stage X rows (16 x 64 floats == 256 float4, one per thread) ----
    {
        const float4* xg = (const float4*)(X + chunk * ROWS_PER_BLOCK_ * IN_);
        ((float4*)xs)[tid] = xg[tid];
    }

    // ---- per-thread residual max|M - I| over a 64-entry segment ---------
    float mloc = 0.0f;
    {
        const int row     = tid >> 1;
        const int colbase = (tid & 1) * 64;
        const float4* mrow = (const float4*)(Mc + row * OUT_ + colbase);
        #pragma unroll
        for (int j4 = 0; j4 < 16; ++j4) {
            float4 v = mrow[j4];
            int cb = colbase + j4 * 4;
            float a0 = v.x - ((cb + 0) == row ? 1.0f : 0.0f);
            float a1 = v.y - ((cb + 1) == row ? 1.0f : 0.0f);
            float a2 = v.z - ((cb + 2) == row ? 1.0f : 0.0f);
            float a3 = v.w - ((cb + 3) == row ? 1.0f : 0.0f);
            mloc = fmaxf(mloc, fmaxf(fmaxf(fabsf(a0), fabsf(a1)),
                                     fmaxf(fabsf(a2), fabsf(a3))));
        }
    }

    // ---- per-column parameters -----------------------------------------
    float dinv[4], bt[4], nl1d[4];
    #pragma unroll
    for (int j = 0; j < 4; ++j) {
        int o = 4 * k + j;
        float diag = Mc[o * OUT_ + o];
        dinv[j] = 1.0f / (LBD2_ + diag);
        bt[j]   = sqrtf(1.0f) * bvec[c * OUT_ + o];   // sqrt(ALPHA)*b
        nl1d[j] = -LBD1_ * dinv[j];
    }

    __syncthreads();

    // ---- Wx for 2 rows x 4 cols ----------------------------------------
    float wx0[4] = {0.f, 0.f, 0.f, 0.f};
    float wx1[4] = {0.f, 0.f, 0.f, 0.f};
    {
        const float* xr0 = xs + (r0 + 0) * IN_;
        const float* xr1 = xs + (r0 + 1) * IN_;
        #pragma unroll
        for (int is = 0; is < 16; ++is) {
            float4 a4 = ((const float4*)xr0)[is];
            float4 b4 = ((const float4*)xr1)[is];
            float ax[4] = {a4.x, a4.y, a4.z, a4.w};
            float bxv[4] = {b4.x, b4.y, b4.z, b4.w};
            #pragma unroll
            for (int q = 0; q < 4; ++q) {
                const int i = is * 4 + q;
                float4 w4 = *(const float4*)(smem + i * WT_PITCH_ + 4 * k);
                wx0[0] = fmaf(w4.x, ax[q], wx0[0]);
                wx0[1] = fmaf(w4.y, ax[q], wx0[1]);
                wx0[2] = fmaf(w4.z, ax[q], wx0[2]);
                wx0[3] = fmaf(w4.w, ax[q], wx0[3]);
                wx1[0] = fmaf(w4.x, bxv[q], wx1[0]);
                wx1[1] = fmaf(w4.y, bxv[q], wx1[1]);
                wx1[2] = fmaf(w4.z, bxv[q], wx1[2]);
                wx1[3] = fmaf(w4.w, bxv[q], wx1[3]);
            }
        }
    }

    // ---- reduce M residual -> block flag --------------------------------
    #pragma unroll
    for (int off = 32; off > 0; off >>= 1)
        mloc = fmaxf(mloc, __shfl_down(mloc, off));
    if ((tid & 63) == 0) red[tid >> 6] = mloc;
    __syncthreads();   // also separates WT reads from Y_lds reuse
    const bool m_zero =
        (fmaxf(fmaxf(red[0], red[1]), fmaxf(red[2], red[3])) == 0.0f);

    // ---- derived per-element constants ----------------------------------
    float wxb0[4], wxb1[4], wd0[4], wd1[4];
    #pragma unroll
    for (int j = 0; j < 4; ++j) {
        wxb0[j] = wx0[j] - bt[j];
        wxb1[j] = wx1[j] - bt[j];
        wd0[j]  = wxb0[j] * dinv[j];
        wd1[j]  = wxb1[j] * dinv[j];
    }

    float y0[4] = {0.f, 0.f, 0.f, 0.f};
    float y1[4] = {0.f, 0.f, 0.f, 0.f};

    if (m_zero) {
        // M_off == 0 exactly: y' = max(((1-dt)y + dt*wxb - l1)*dinv, 0)
        //                        = max(fma(A, y, fma(dt, wd, nl1d)), 0)
        for (int it = 0; it < MAXITER_; ++it) {
            float cf = (float)it;
            float dt = fmaxf(0.05f / (1.0f + cf / 10.0f), 0.01f);
            #pragma unroll
            for (int j = 0; j < 4; ++j) {
                float A  = fmaf(-dt, dinv[j], dinv[j]);   // (1-dt)*dinv
                float D0 = fmaf(dt, wd0[j], nl1d[j]);
                float D1 = fmaf(dt, wd1[j], nl1d[j]);
                y0[j] = fmaxf(fmaf(A, y0[j], D0), 0.0f);
                y1[j] = fmaxf(fmaf(A, y1[j], D1), 0.0f);
            }
        }
    } else {
        // General path (correct, slow; not taken by the bench input).
        float* Ylds = smem;   // 16 x 128
        for (int it = 0; it < MAXITER_; ++it) {
            float cf = (float)it;
            float dt = fmaxf(0.05f / (1.0f + cf / 10.0f), 0.01f);
            #pragma unroll
            for (int j = 0; j < 4; ++j) {
                Ylds[(r0 + 0) * OUT_ + 4 * k + j] = y0[j];
                Ylds[(r0 + 1) * OUT_ + 4 * k + j] = y1[j];
            }
            __syncthreads();
            float my0[4] = {0.f, 0.f, 0.f, 0.f};
            float my1[4] = {0.f, 0.f, 0.f, 0.f};
            for (int o = 0; o < OUT_; ++o) {
                float ya = Ylds[(r0 + 0) * OUT_ + o];
                float yb = Ylds[(r0 + 1) * OUT_ + o];
                #pragma unroll
                for (int j = 0; j < 4; ++j) {
                    int p = 4 * k + j;
                    float moff = Mc[p * OUT_ + o] - (o == p ? 1.0f : 0.0f);
                    my0[j] = fmaf(ya, moff, my0[j]);
                    my1[j] = fmaf(yb, moff, my1[j]);
                }
            }
            #pragma unroll
            for (int j = 0; j < 4; ++j) {
                float uy0 = fmaf(dt, wxb0[j] - y0[j] - my0[j], y0[j]);
                float uy1 = fmaf(dt, wxb1[j] - y1[j] - my1[j], y1[j]);
                y0[j] = fmaxf((uy0 - LBD1_) * dinv[j], 0.0f);
                y1[j] = fmaxf((uy1 - LBD1_) * dinv[j], 0.0f);
            }
            __syncthreads();
        }
    }

    // ---- store Y: out[c][b][o], coalesced float4 ------------------------
    float* op0 = out + c * (B_ * OUT_) + (rowg0 + 0) * OUT_ + 4 * k;
    float* op1 = out + c * (B_ * OUT_) + (rowg0 + 1) * OUT_ + 4 * k;
    float4 s0 = {y0[0], y0[1], y0[2], y0[3]};
    float4 s1 = {y1[0], y1[1], y1[2], y1[3]};
    *(float4*)op0 = s0;
    *(float4*)op1 = s1;
}

extern "C" void kernel_launch(void* const* d_in, const int* in_sizes, int n_in,
                              void* d_out, int out_size, void* d_ws, size_t ws_size,
                              hipStream_t stream)
{
    const float* X  = (const float*)d_in[0];   // [B, IN]
    const float* W  = (const float*)d_in[1];   // [C, OUT, IN]
    const float* M  = (const float*)d_in[2];   // [C, OUT, OUT]
    const float* bv = (const float*)d_in[3];   // [C, OUT]
    // d_in[4] = errTrack: provably unused (loop never converges early)
    float* out = (float*)d_out;                // [C, B, OUT]

    const int blocks = C_ * (B_ / ROWS_PER_BLOCK_);   // 4 * 128 = 512
    pcn_kernel<<<blocks, THREADS_, 0, stream>>>(X, W, M, bv, out);
}

// Round 2
// 73.160 us; speedup vs baseline: 1.2989x; 1.2989x over previous
//
#include <hip/hip_runtime.h>
#include <math.h>

// PlaceCellNetwork: C=4, B=2048, IN=64, OUT=128, 100 fixed-point iterations.
//
// Key result (round 2): with M == I (the actual input, verified EXACTLY in
// kernel via a bitwise M==I check), the per-element iteration
//   y <- max(((1-dt_n) y + dt_n*wx - l1)/1.005, 0)
// collapses in closed form. Unclamped trajectory is affine in wx:
//   y_n = P_n*wx + Q_n,  P_{n+1} = A_n P_n + dinv*dt_n, Q_{n+1} = A_n Q_n - dinv*l1,
//   A_n = (1-dt_n)*dinv. The clamp-boundary ratio is monotone non-decreasing
// (dt_n non-increasing), so the binding positivity constraint is iteration 100,
// and once clamped y stays 0 (D_m <= 0 thereafter). Hence EXACTLY:
//   y_final = max(P_100*wx + Q_100, 0).
// P,Q computed on host in double (fp32 dt schedule mimicked). The general
// M != I path keeps the full verified iteration loop (never taken by bench).

#define C_ 4
#define IN_ 64
#define OUT_ 128
#define B_ 2048
#define MAXITER_ 100
#define LBD1_ 0.005f
#define LBD2_ 0.005f

#define THREADS_ 256
#define ROWS_PER_BLOCK_ 16   // 2 rows/thread, 32 col-threads (4 cols each)
#define WT_PITCH_ 132        // conflict-free transpose writes + aligned b128 rows

__global__ __launch_bounds__(THREADS_)
void pcn_kernel(const float* __restrict__ X,
                const float* __restrict__ W,
                const float* __restrict__ M,
                const float* __restrict__ bvec,
                float* __restrict__ out,
                float Pc, float Qc)
{
    __shared__ __align__(16) float smem[IN_ * WT_PITCH_];   // W^T; reused as Y in general path
    __shared__ __align__(16) float xs[ROWS_PER_BLOCK_ * IN_];
    __shared__ unsigned red[4];

    const int tid   = threadIdx.x;
    const int bx    = blockIdx.x;
    const int c     = bx >> 7;        // 128 chunks per c
    const int chunk = bx & 127;
    const int k     = tid & 31;       // cols 4k..4k+3
    const int rg    = tid >> 5;       // 0..7
    const int r0    = 2 * rg;
    const int rowg0 = chunk * ROWS_PER_BLOCK_ + r0;

    const float* Wc = W + c * (OUT_ * IN_);
    const float* Mc = M + c * (OUT_ * OUT_);

    // ---- stage W^T into LDS: WT[i][o] = W[o][i] ------------------------
    {
        const int o    = tid >> 1;
        const int half = tid & 1;
        const float4* wrow = (const float4*)(Wc + o * IN_ + half * 32);
        #pragma unroll
        for (int j4 = 0; j4 < 8; ++j4) {
            float4 v = wrow[j4];
            int i0 = half * 32 + j4 * 4;
            smem[(i0 + 0) * WT_PITCH_ + o] = v.x;
            smem[(i0 + 1) * WT_PITCH_ + o] = v.y;
            smem[(i0 + 2) * WT_PITCH_ + o] = v.z;
            smem[(i0 + 3) * WT_PITCH_ + o] = v.w;
        }
    }
    // ---- stage X rows (16 x 64 floats == 256 float4) --------------------
    {
        const float4* xg = (const float4*)(X + chunk * ROWS_PER_BLOCK_ * IN_);
        ((float4*)xs)[tid] = xg[tid];
    }

    // ---- bitwise M == I check over this thread's 64-entry segment -------
    unsigned bad = 0;
    {
        const int row     = tid >> 1;
        const int colbase = (tid & 1) * 64;
        const uint4* mrow = (const uint4*)(Mc + row * OUT_ + colbase);
        #pragma unroll
        for (int j4 = 0; j4 < 16; ++j4) {
            uint4 v = mrow[j4];
            int cb = colbase + j4 * 4;
            bad |= v.x ^ ((cb + 0) == row ? 0x3F800000u : 0u);
            bad |= v.y ^ ((cb + 1) == row ? 0x3F800000u : 0u);
            bad |= v.z ^ ((cb + 2) == row ? 0x3F800000u : 0u);
            bad |= v.w ^ ((cb + 3) == row ? 0x3F800000u : 0u);
        }
    }

    // ---- per-column parameters -----------------------------------------
    float dinv[4], bt[4], g[4];
    #pragma unroll
    for (int j = 0; j < 4; ++j) {
        int o = 4 * k + j;
        float diag = Mc[o * OUT_ + o];
        dinv[j] = 1.0f / (LBD2_ + diag);
        bt[j]   = bvec[c * OUT_ + o];          // sqrt(ALPHA)=1
        g[j]    = fmaf(-Pc, bt[j], Qc);        // fast-path constant: Qc - Pc*b
    }

    __syncthreads();

    // ---- Wx for 2 rows x 4 cols ----------------------------------------
    float wx0[4] = {0.f, 0.f, 0.f, 0.f};
    float wx1[4] = {0.f, 0.f, 0.f, 0.f};
    {
        const float* xr0 = xs + (r0 + 0) * IN_;
        const float* xr1 = xs + (r0 + 1) * IN_;
        #pragma unroll
        for (int is = 0; is < 16; ++is) {
            float4 a4 = ((const float4*)xr0)[is];
            float4 b4 = ((const float4*)xr1)[is];
            float ax[4]  = {a4.x, a4.y, a4.z, a4.w};
            float bxv[4] = {b4.x, b4.y, b4.z, b4.w};
            #pragma unroll
            for (int q = 0; q < 4; ++q) {
                const int i = is * 4 + q;
                float4 w4 = *(const float4*)(smem + i * WT_PITCH_ + 4 * k);
                wx0[0] = fmaf(w4.x, ax[q], wx0[0]);
                wx0[1] = fmaf(w4.y, ax[q], wx0[1]);
                wx0[2] = fmaf(w4.z, ax[q], wx0[2]);
                wx0[3] = fmaf(w4.w, ax[q], wx0[3]);
                wx1[0] = fmaf(w4.x, bxv[q], wx1[0]);
                wx1[1] = fmaf(w4.y, bxv[q], wx1[1]);
                wx1[2] = fmaf(w4.z, bxv[q], wx1[2]);
                wx1[3] = fmaf(w4.w, bxv[q], wx1[3]);
            }
        }
    }

    // ---- reduce M check -> block flag -----------------------------------
    #pragma unroll
    for (int off = 32; off > 0; off >>= 1)
        bad |= __shfl_down(bad, off);
    if ((tid & 63) == 0) red[tid >> 6] = bad;
    __syncthreads();   // also separates WT reads from Y_lds reuse (general path)
    const bool m_ident = ((red[0] | red[1] | red[2] | red[3]) == 0u);

    float y0[4], y1[4];

    if (m_ident) {
        // ---- closed form: y = max(P*wx + (Q - P*b), 0) ------------------
        #pragma unroll
        for (int j = 0; j < 4; ++j) {
            y0[j] = fmaxf(fmaf(Pc, wx0[j], g[j]), 0.0f);
            y1[j] = fmaxf(fmaf(Pc, wx1[j], g[j]), 0.0f);
        }
    } else {
        // ---- general path: full verified iteration loop -----------------
        float wxb0[4], wxb1[4];
        #pragma unroll
        for (int j = 0; j < 4; ++j) {
            wxb0[j] = wx0[j] - bt[j];
            wxb1[j] = wx1[j] - bt[j];
            y0[j] = 0.f; y1[j] = 0.f;
        }
        float* Ylds = smem;   // 16 x 128
        for (int it = 0; it < MAXITER_; ++it) {
            float cf = (float)it;
            float dt = fmaxf(0.05f / (1.0f + cf / 10.0f), 0.01f);
            #pragma unroll
            for (int j = 0; j < 4; ++j) {
                Ylds[(r0 + 0) * OUT_ + 4 * k + j] = y0[j];
                Ylds[(r0 + 1) * OUT_ + 4 * k + j] = y1[j];
            }
            __syncthreads();
            float my0[4] = {0.f, 0.f, 0.f, 0.f};
            float my1[4] = {0.f, 0.f, 0.f, 0.f};
            for (int o = 0; o < OUT_; ++o) {
                float ya = Ylds[(r0 + 0) * OUT_ + o];
                float yb = Ylds[(r0 + 1) * OUT_ + o];
                #pragma unroll
                for (int j = 0; j < 4; ++j) {
                    int p = 4 * k + j;
                    float moff = Mc[p * OUT_ + o] - (o == p ? 1.0f : 0.0f);
                    my0[j] = fmaf(ya, moff, my0[j]);
                    my1[j] = fmaf(yb, moff, my1[j]);
                }
            }
            #pragma unroll
            for (int j = 0; j < 4; ++j) {
                float uy0 = fmaf(dt, wxb0[j] - y0[j] - my0[j], y0[j]);
                float uy1 = fmaf(dt, wxb1[j] - y1[j] - my1[j], y1[j]);
                y0[j] = fmaxf((uy0 - LBD1_) * dinv[j], 0.0f);
                y1[j] = fmaxf((uy1 - LBD1_) * dinv[j], 0.0f);
            }
            __syncthreads();
        }
    }

    // ---- store Y: out[c][b][o], coalesced float4 ------------------------
    float* op0 = out + c * (B_ * OUT_) + (rowg0 + 0) * OUT_ + 4 * k;
    float* op1 = out + c * (B_ * OUT_) + (rowg0 + 1) * OUT_ + 4 * k;
    float4 s0 = {y0[0], y0[1], y0[2], y0[3]};
    float4 s1 = {y1[0], y1[1], y1[2], y1[3]};
    *(float4*)op0 = s0;
    *(float4*)op1 = s1;
}

extern "C" void kernel_launch(void* const* d_in, const int* in_sizes, int n_in,
                              void* d_out, int out_size, void* d_ws, size_t ws_size,
                              hipStream_t stream)
{
    const float* X  = (const float*)d_in[0];   // [B, IN]
    const float* W  = (const float*)d_in[1];   // [C, OUT, IN]
    const float* M  = (const float*)d_in[2];   // [C, OUT, OUT]
    const float* bv = (const float*)d_in[3];   // [C, OUT]
    // d_in[4] = errTrack: unused (loop provably never converges early)
    float* out = (float*)d_out;                // [C, B, OUT]

    // Host-side closed-form constants for the M==I fast path.
    // Mimic the reference's fp32 dt schedule; aggregate in double (exact
    // relative to the reference's own fp32 drift; absmax threshold 0.48).
    const double dinv = 1.0 / (double)(1.0f + LBD2_);   // 1/1.005
    double P = 0.0, Q = 0.0;
    for (int n = 0; n < MAXITER_; ++n) {
        float dtf = fmaxf(0.05f / (1.0f + (float)n / 10.0f), 0.01f);
        double dt = (double)dtf;
        double A  = (1.0 - dt) * dinv;
        P = A * P + dinv * dt;
        Q = A * Q - dinv * (double)LBD1_;
    }

    const int blocks = C_ * (B_ / ROWS_PER_BLOCK_);   // 512
    pcn_kernel<<<blocks, THREADS_, 0, stream>>>(X, W, M, bv, out,
                                                (float)P, (float)Q);
}

// Round 3
// 70.176 us; speedup vs baseline: 1.3541x; 1.0425x over previous
//
#include <hip/hip_runtime.h>
#include <math.h>

// PlaceCellNetwork: C=4, B=2048, IN=64, OUT=128, 100 fixed-point iterations.
//
// With M == I (the actual input, verified EXACTLY via bitwise check), the
// per-element iteration collapses in closed form (see round-2 derivation):
//   y_final = max(P_100*wx + Q_100 - P_100*b, 0)   exactly,
// since the clamp-boundary ratio is monotone (dt non-increasing) and a
// clamped element stays clamped. P,Q computed on host in double.
//
// Round-3 restructure: wave owns 4 rows x 128 cols (lane owns 2 cols).
// X row addresses are wave-uniform -> readfirstlane + uniform loads (no LDS
// staging/reads for X at all). W fragment reads become 64 ds_read_b64/wave,
// reused across 4 rows: per-CU LDS cycles ~2x lower than round 2.

#define C_ 4
#define IN_ 64
#define OUT_ 128
#define B_ 2048
#define MAXITER_ 100
#define LBD1_ 0.005f
#define LBD2_ 0.005f

#define THREADS_ 256
#define ROWS_PER_BLOCK_ 16   // 4 waves x 4 rows
#define WT_PITCH_ 132        // conflict-free transpose writes; (132i+2l) stays 8B-aligned

__global__ __launch_bounds__(THREADS_)
void pcn_kernel(const float* __restrict__ X,
                const float* __restrict__ W,
                const float* __restrict__ M,
                const float* __restrict__ bvec,
                float* __restrict__ out,
                float Pc, float Qc)
{
    __shared__ __align__(16) float smem[IN_ * WT_PITCH_];   // W^T; reused as Y (16x128) in general path
    __shared__ unsigned red[4];

    const int tid   = threadIdx.x;
    const int bx    = blockIdx.x;
    const int c     = bx >> 7;        // 128 chunks per c
    const int chunk = bx & 127;
    const int wv    = tid >> 6;       // wave 0..3
    const int lane  = tid & 63;
    const int p0    = 2 * lane;       // owned cols p0, p0+1

    const float* Wc = W + c * (OUT_ * IN_);
    const float* Mc = M + c * (OUT_ * OUT_);

    // ---- stage W^T into LDS: WT[i][o] = W[o][i] (2-way write alias = free) --
    {
        const int o    = tid >> 1;
        const int half = tid & 1;
        const float4* wrow = (const float4*)(Wc + o * IN_ + half * 32);
        #pragma unroll
        for (int j4 = 0; j4 < 8; ++j4) {
            float4 v = wrow[j4];
            int i0 = half * 32 + j4 * 4;
            smem[(i0 + 0) * WT_PITCH_ + o] = v.x;
            smem[(i0 + 1) * WT_PITCH_ + o] = v.y;
            smem[(i0 + 2) * WT_PITCH_ + o] = v.z;
            smem[(i0 + 3) * WT_PITCH_ + o] = v.w;
        }
    }

    // ---- bitwise M == I check over this thread's 64-entry segment ----------
    unsigned bad = 0;
    {
        const int row     = tid >> 1;
        const int colbase = (tid & 1) * 64;
        const uint4* mrow = (const uint4*)(Mc + row * OUT_ + colbase);
        #pragma unroll
        for (int j4 = 0; j4 < 16; ++j4) {
            uint4 v = mrow[j4];
            int cb = colbase + j4 * 4;
            bad |= v.x ^ ((cb + 0) == row ? 0x3F800000u : 0u);
            bad |= v.y ^ ((cb + 1) == row ? 0x3F800000u : 0u);
            bad |= v.z ^ ((cb + 2) == row ? 0x3F800000u : 0u);
            bad |= v.w ^ ((cb + 3) == row ? 0x3F800000u : 0u);
        }
    }

    const float2 bv2 = *(const float2*)(bvec + c * OUT_ + p0);

    __syncthreads();

    // ---- Wx: 4 rows x 2 cols per lane; X rows are wave-uniform -------------
    const int row0 = chunk * ROWS_PER_BLOCK_ + wv * 4;           // block-local batch rows
    const float* xrow = X + __builtin_amdgcn_readfirstlane(row0 * IN_);

    float acc[4][2];
    #pragma unroll
    for (int r = 0; r < 4; ++r) { acc[r][0] = 0.f; acc[r][1] = 0.f; }

    #pragma unroll 4
    for (int i4 = 0; i4 < 16; ++i4) {
        float xq[4][4];
        #pragma unroll
        for (int r = 0; r < 4; ++r) {
            float4 v = *(const float4*)(xrow + r * IN_ + 4 * i4);  // uniform -> scalar load
            xq[r][0] = v.x; xq[r][1] = v.y; xq[r][2] = v.z; xq[r][3] = v.w;
        }
        #pragma unroll
        for (int di = 0; di < 4; ++di) {
            const int i = 4 * i4 + di;
            float2 w2 = *(const float2*)(smem + i * WT_PITCH_ + p0);
            #pragma unroll
            for (int r = 0; r < 4; ++r) {
                acc[r][0] = fmaf(w2.x, xq[r][di], acc[r][0]);
                acc[r][1] = fmaf(w2.y, xq[r][di], acc[r][1]);
            }
        }
    }

    // ---- reduce M check -> block flag ---------------------------------------
    #pragma unroll
    for (int off = 32; off > 0; off >>= 1)
        bad |= __shfl_down(bad, off);
    if (lane == 0) red[wv] = bad;
    __syncthreads();   // also fences WT reads before Ylds reuse (general path)
    const bool m_ident = ((red[0] | red[1] | red[2] | red[3]) == 0u);

    float y[4][2];

    if (m_ident) {
        // ---- closed form: y = max(P*wx + (Q - P*b), 0) ----------------------
        const float g0 = fmaf(-Pc, bv2.x, Qc);
        const float g1 = fmaf(-Pc, bv2.y, Qc);
        #pragma unroll
        for (int r = 0; r < 4; ++r) {
            y[r][0] = fmaxf(fmaf(Pc, acc[r][0], g0), 0.0f);
            y[r][1] = fmaxf(fmaf(Pc, acc[r][1], g1), 0.0f);
        }
    } else {
        // ---- general path: full iteration loop (correct; never taken) -------
        const float dinv0 = 1.0f / (LBD2_ + Mc[(p0 + 0) * OUT_ + (p0 + 0)]);
        const float dinv1 = 1.0f / (LBD2_ + Mc[(p0 + 1) * OUT_ + (p0 + 1)]);
        float wxb[4][2];
        #pragma unroll
        for (int r = 0; r < 4; ++r) {
            wxb[r][0] = acc[r][0] - bv2.x;
            wxb[r][1] = acc[r][1] - bv2.y;
            y[r][0] = 0.f; y[r][1] = 0.f;
        }
        float* Ylds = smem;   // 16 x 128
        for (int it = 0; it < MAXITER_; ++it) {
            float dt = fmaxf(0.05f / (1.0f + (float)it / 10.0f), 0.01f);
            #pragma unroll
            for (int r = 0; r < 4; ++r) {
                Ylds[(wv * 4 + r) * OUT_ + p0 + 0] = y[r][0];
                Ylds[(wv * 4 + r) * OUT_ + p0 + 1] = y[r][1];
            }
            __syncthreads();
            float my[4][2];
            #pragma unroll
            for (int r = 0; r < 4; ++r) { my[r][0] = 0.f; my[r][1] = 0.f; }
            for (int o = 0; o < OUT_; ++o) {
                float m0 = Mc[(p0 + 0) * OUT_ + o] - (o == p0 + 0 ? 1.0f : 0.0f);
                float m1 = Mc[(p0 + 1) * OUT_ + o] - (o == p0 + 1 ? 1.0f : 0.0f);
                #pragma unroll
                for (int r = 0; r < 4; ++r) {
                    float yo = Ylds[(wv * 4 + r) * OUT_ + o];
                    my[r][0] = fmaf(yo, m0, my[r][0]);
                    my[r][1] = fmaf(yo, m1, my[r][1]);
                }
            }
            #pragma unroll
            for (int r = 0; r < 4; ++r) {
                float uy0 = fmaf(dt, wxb[r][0] - y[r][0] - my[r][0], y[r][0]);
                float uy1 = fmaf(dt, wxb[r][1] - y[r][1] - my[r][1], y[r][1]);
                y[r][0] = fmaxf((uy0 - LBD1_) * dinv0, 0.0f);
                y[r][1] = fmaxf((uy1 - LBD1_) * dinv1, 0.0f);
            }
            __syncthreads();
        }
    }

    // ---- store Y: out[c][b][o], lanes cover 128 contiguous cols -------------
    #pragma unroll
    for (int r = 0; r < 4; ++r) {
        float2 s = {y[r][0], y[r][1]};
        *(float2*)(out + (c * B_ + row0 + r) * OUT_ + p0) = s;
    }
}

extern "C" void kernel_launch(void* const* d_in, const int* in_sizes, int n_in,
                              void* d_out, int out_size, void* d_ws, size_t ws_size,
                              hipStream_t stream)
{
    const float* X  = (const float*)d_in[0];   // [B, IN]
    const float* W  = (const float*)d_in[1];   // [C, OUT, IN]
    const float* M  = (const float*)d_in[2];   // [C, OUT, OUT]
    const float* bv = (const float*)d_in[3];   // [C, OUT]
    // d_in[4] = errTrack: unused (loop provably never converges early)
    float* out = (float*)d_out;                // [C, B, OUT]

    // Closed-form constants for the M==I fast path (fp32 dt schedule, double agg).
    const double dinv = 1.0 / (double)(1.0f + LBD2_);   // 1/1.005
    double P = 0.0, Q = 0.0;
    for (int n = 0; n < MAXITER_; ++n) {
        float dtf = fmaxf(0.05f / (1.0f + (float)n / 10.0f), 0.01f);
        double dt = (double)dtf;
        double A  = (1.0 - dt) * dinv;
        P = A * P + dinv * dt;
        Q = A * Q - dinv * (double)LBD1_;
    }

    const int blocks = C_ * (B_ / ROWS_PER_BLOCK_);   // 512, 2 per CU
    pcn_kernel<<<blocks, THREADS_, 0, stream>>>(X, W, M, bv, out,
                                                (float)P, (float)Q);
}